// Round 7
// baseline (379.526 us; speedup 1.0000x reference)
//
#include <hip/hip_runtime.h>
#include <hip/hip_bf16.h>

typedef unsigned short u16;
typedef __attribute__((ext_vector_type(8))) short  bf16x8;
typedef __attribute__((ext_vector_type(8))) u16    u16x8;
typedef __attribute__((ext_vector_type(4))) float  fx4;
typedef __attribute__((ext_vector_type(16))) float fx16;

// flat offsets of TT cores in the packed kernel (reference iterates k=3..0 from idx 0)
#define OFF_C0 0       // core for k=3: [8 x 256]   core0[i4][a3*8+o4]
#define OFF_C1 2048    // core for k=2: [256 x 256] core1[i3*32+a3][a2*8+o3]
#define OFF_C2 67584   // core for k=1: [256 x 256] core2[i2*32+a2][a1*8+o2]
#define OFF_C3 133120  // core for k=0: [256 x 8]   core3[i1*32+a1][o1]

// Fragment-major layouts (32x32x16 MFMA, verified on-chip in R2):
//   A-operand: lane l holds A[m32*32 + (l&31)][k32*32 + ks*16 + (l>>5)*8 + e], e=0..7
//   xbt/wtt flat elem index: (((k32*128 + m32)*2 + ks)*64 + l)*8 + e
// So each (k32, m32, ks) unit is 1024 contiguous bytes in exact wave-lane order:
// gld16 staging reads are fully contiguous, LDS stays linear, ds_read_b128 is lane-linear.

static __device__ __forceinline__ u16 f2bf(float f) {
  union { __hip_bfloat16 h; u16 u; } cv;
  cv.h = __float2bfloat16(f);
  return cv.u;
}
static __device__ __forceinline__ float bf2f(u16 u) {
  union { u16 u; __hip_bfloat16 h; } cv;
  cv.u = u;
  return __bfloat162float(cv.h);
}

// fused: blocks [0,8192): x fp32 -> bf16 in fragment-major xbt; blocks [8192,8704): W34T.
__global__ void x_and_w34T(const float* __restrict__ x, u16* __restrict__ xbt,
                           const float* __restrict__ ker, float* __restrict__ w34T) {
  if (blockIdx.x < 8192) {
    int t = blockIdx.x * 256 + threadIdx.x;        // 2,097,152 threads, one 16B chunk each
    int l = t & 63, ks = (t >> 6) & 1, m32 = (t >> 7) & 127, k32 = t >> 14;
    int row = m32 * 32 + (l & 31);
    int col = k32 * 32 + ks * 16 + (l >> 5) * 8;
    const fx4* p = (const fx4*)(x + (size_t)row * 4096 + col);
    fx4 v0 = p[0], v1 = p[1];
    u16 tmp[8];
#pragma unroll
    for (int q = 0; q < 4; ++q) tmp[q] = f2bf(v0[q]);
#pragma unroll
    for (int q = 0; q < 4; ++q) tmp[4 + q] = f2bf(v1[q]);
    *(u16x8*)(xbt + (size_t)t * 8) = *(const u16x8*)tmp;
  } else {
    int t = (blockIdx.x - 8192) * 256 + threadIdx.x;   // 131072 threads
    int i34 = t & 63, c = t >> 6;
    int a2 = c >> 6, o3 = (c >> 3) & 7, o4 = c & 7;
    int i3 = i34 >> 3, i4 = i34 & 7;
    float s = 0.f;
#pragma unroll 8
    for (int a3 = 0; a3 < 32; ++a3) {
      float k1 = ker[OFF_C1 + (i3 * 32 + a3) * 256 + a2 * 8 + o3];
      float k0 = ker[OFF_C0 + i4 * 256 + a3 * 8 + o4];
      s += k1 * k0;
    }
    w34T[c * 64 + i34] = s;
  }
}

// W234t[(a1*64+o2*8+o3)*8 + o4][i234] = sum_a2 core2[i2*32+a2, a1*8+o2] * W34T[a2*64+o3*8+o4][i34]
__global__ void build_w234t2(const float* __restrict__ ker, const float* __restrict__ w34T,
                             u16* __restrict__ w234t) {
  int t = blockIdx.x * 256 + threadIdx.x;   // 131072 threads
  int i234 = t & 511, g = t >> 9;           // g = a1*8 + o3
  int a1 = g >> 3, o3 = g & 7;
  int i2 = i234 >> 6, i34 = i234 & 63;
  float acc[8][8];
#pragma unroll
  for (int a = 0; a < 8; ++a)
#pragma unroll
    for (int b = 0; b < 8; ++b) acc[a][b] = 0.f;
  for (int a2 = 0; a2 < 32; ++a2) {
    float w[8];
#pragma unroll
    for (int o4 = 0; o4 < 8; ++o4)
      w[o4] = w34T[(a2 * 64 + o3 * 8 + o4) * 64 + i34];
#pragma unroll
    for (int o2 = 0; o2 < 8; ++o2) {
      float c2 = ker[OFF_C2 + (i2 * 32 + a2) * 256 + a1 * 8 + o2];
#pragma unroll
      for (int o4 = 0; o4 < 8; ++o4) acc[o2][o4] += c2 * w[o4];
    }
  }
#pragma unroll
  for (int o2 = 0; o2 < 8; ++o2) {
    int cg = a1 * 64 + o2 * 8 + o3;
#pragma unroll
    for (int o4 = 0; o4 < 8; ++o4)
      w234t[(cg * 8 + o4) * 512 + i234] = f2bf(acc[o2][o4]);
  }
}

// Wt[j,i] -> fragment-major wtt. Thread owns (j234, i234), reads each w234t element once.
__global__ void build_wt3(const float* __restrict__ ker, const u16* __restrict__ w234t,
                          u16* __restrict__ wtt) {
  int t = blockIdx.x * 256 + threadIdx.x;   // 262144 threads
  int i234 = t & 511, j234 = t >> 9;
  float acc[8][8];
#pragma unroll
  for (int a = 0; a < 8; ++a)
#pragma unroll
    for (int b = 0; b < 8; ++b) acc[a][b] = 0.f;
  for (int a1 = 0; a1 < 32; ++a1) {
    float w = bf2f(w234t[(a1 * 512 + j234) * 512 + i234]);
#pragma unroll
    for (int i1 = 0; i1 < 8; ++i1) {
      const float* c3 = ker + OFF_C3 + (i1 * 32 + a1) * 8;
#pragma unroll
      for (int o1 = 0; o1 < 8; ++o1) acc[i1][o1] += c3[o1] * w;
    }
  }
  // dest: j = o1*512 + j234 (N), i = i1*512 + i234 (K)
  const int ks = (i234 >> 4) & 1;
  const int l  = (j234 & 31) | (((i234 >> 3) & 1) << 5);
  const int e  = i234 & 7;
#pragma unroll
  for (int o1 = 0; o1 < 8; ++o1) {
    const int n32 = o1 * 16 + (j234 >> 5);
#pragma unroll
    for (int i1 = 0; i1 < 8; ++i1) {
      const int k32 = i1 * 16 + (i234 >> 5);
      wtt[(((size_t)(k32 * 128 + n32) * 2 + ks) * 64 + l) * 8 + e] = f2bf(acc[i1][o1]);
    }
  }
}

__device__ __forceinline__ void gld16(const u16* g, u16* l) {
  __builtin_amdgcn_global_load_lds((const __attribute__((address_space(1))) void*)g,
                                   (__attribute__((address_space(3))) void*)l, 16, 0, 0);
}

// C[4096,4096] = A*B^T + bias from fragment-major xbt/wtt.
// 256x256 tile, BK=32, 4 waves (2Mx2N), per-wave 128x128 = 4x4 frags of 32x32x16 MFMA.
// LDS: 3 buf x (A 16KB + B 16KB) = 96 KB, all transfers linear (contiguous gld16 source,
// lane-linear ds_read_b128 - structurally conflict-free). Free-run: 16 ds_read + 8 gld16
// (stage t+2) + 32 MFMA + vmcnt(8) + one barrier.
__global__ __launch_bounds__(256, 1) void gemm_fm(const u16* __restrict__ A, const u16* __restrict__ B,
                                                  const float* __restrict__ bias, float* __restrict__ C) {
  __shared__ __align__(16) u16 sh[49152];  // elems: A bufs [0, 24576), B bufs [24576, 49152)

  const int tid = threadIdx.x;
  const int lane = tid & 63;
  const int wave = tid >> 6;
  const int wm = wave >> 1, wn = wave & 1;
  const int l32 = lane & 31, hk = lane >> 5;

  // XCD-aware block swizzle (256 blocks, 256%8==0)
  const int bid = blockIdx.x;
  const int wg = (bid & 7) * 32 + (bid >> 3);
  const int bm = (wg >> 4) * 256, bn = (wg & 15) * 256;

  // staging: wave w stages A-units w*4..w*4+3 and B-units w*4..w*4+3 (unit = (mf,ks), 1KB)
  size_t agA[4], agB[4];
#pragma unroll
  for (int j = 0; j < 4; ++j) {
    const int u = wave * 4 + j, mf = u >> 1, ks = u & 1;
    agA[j] = ((size_t)((bm >> 5) + mf) * 2 + ks) * 512 + lane * 8;
    agB[j] = ((size_t)((bn >> 5) + mf) * 2 + ks) * 512 + lane * 8;
  }
  const int ldsU = wave * 4 * 512;  // elems: this wave's first unit within a buffer

  fx16 acc[4][4];
#pragma unroll
  for (int m = 0; m < 4; ++m)
#pragma unroll
    for (int n = 0; n < 4; ++n)
#pragma unroll
      for (int q = 0; q < 16; ++q) acc[m][n][q] = 0.f;

#define STAGE(buf, tt) do { const size_t ko = (size_t)((tt) & 127) * 131072; \
    u16* a_ = sh + (buf) * 8192 + ldsU; u16* b_ = sh + 24576 + (buf) * 8192 + ldsU; \
    gld16(A + agA[0] + ko, a_); \
    gld16(A + agA[1] + ko, a_ + 512); \
    gld16(A + agA[2] + ko, a_ + 1024); \
    gld16(A + agA[3] + ko, a_ + 1536); \
    gld16(B + agB[0] + ko, b_); \
    gld16(B + agB[1] + ko, b_ + 512); \
    gld16(B + agB[2] + ko, b_ + 1024); \
    gld16(B + agB[3] + ko, b_ + 1536); } while (0)

  // prologue: stage tiles 0,1 (16 loads); wait tile 0 (retire 8)
  STAGE(0, 0);
  STAGE(1, 1);
  asm volatile("s_waitcnt vmcnt(8)" ::: "memory");
  __builtin_amdgcn_s_barrier();

  int p = 0;
  for (int t = 0; t < 128; ++t) {
    const int ps = p + 2 >= 3 ? p - 1 : p + 2;   // buf of tile t+2
    const u16* Ap = sh + p * 8192;
    const u16* Bp = sh + 24576 + p * 8192;

    // lane-linear fragment reads: unit u at byte u*1024 + lane*16
    bf16x8 a0[4], b0[4], a1[4], b1[4];
#pragma unroll
    for (int m = 0; m < 4; ++m) {
      a0[m] = *(const bf16x8*)(Ap + (wm * 8 + m * 2) * 512 + lane * 8);
      a1[m] = *(const bf16x8*)(Ap + (wm * 8 + m * 2 + 1) * 512 + lane * 8);
    }
#pragma unroll
    for (int n = 0; n < 4; ++n) {
      b0[n] = *(const bf16x8*)(Bp + (wn * 8 + n * 2) * 512 + lane * 8);
      b1[n] = *(const bf16x8*)(Bp + (wn * 8 + n * 2 + 1) * 512 + lane * 8);
    }

    STAGE(ps, t + 2);

    __builtin_amdgcn_s_setprio(1);
#pragma unroll
    for (int m = 0; m < 4; ++m)
#pragma unroll
      for (int n = 0; n < 4; ++n)
        acc[m][n] = __builtin_amdgcn_mfma_f32_32x32x16_bf16(a0[m], b0[n], acc[m][n], 0, 0, 0);
#pragma unroll
    for (int m = 0; m < 4; ++m)
#pragma unroll
      for (int n = 0; n < 4; ++n)
        acc[m][n] = __builtin_amdgcn_mfma_f32_32x32x16_bf16(a1[m], b1[n], acc[m][n], 0, 0, 0);
    __builtin_amdgcn_s_setprio(0);

    asm volatile("s_waitcnt vmcnt(8)" ::: "memory");  // retire tile t+1's 8 loads
    __builtin_amdgcn_s_barrier();
    p = p + 1 >= 3 ? 0 : p + 1;
  }

  // epilogue: C/D layout col=lane&31, row=(reg&3)+8*(reg>>2)+4*(lane>>5)  [m74/m101, R2-verified]
#pragma unroll
  for (int n = 0; n < 4; ++n) {
    const int col = bn + wn * 128 + n * 32 + l32;
    const float bvl = bias[col];
#pragma unroll
    for (int m = 0; m < 4; ++m) {
      const int r0 = bm + wm * 128 + m * 32 + 4 * hk;
#pragma unroll
      for (int q = 0; q < 16; ++q) {
        const int row = r0 + (q & 3) + 8 * (q >> 2);
        C[(size_t)row * 4096 + col] = acc[m][n][q] + bvl;
      }
    }
  }
#undef STAGE
}

extern "C" void kernel_launch(void* const* d_in, const int* in_sizes, int n_in,
                              void* d_out, int out_size, void* d_ws, size_t ws_size,
                              hipStream_t stream) {
  const float* x    = (const float*)d_in[0];
  const float* ker  = (const float*)d_in[1];
  const float* bias = (const float*)d_in[2];
  float* out = (float*)d_out;

  char* ws = (char*)d_ws;
  u16*  xbt   = (u16*)ws;                      // 32 MB  bf16 x, fragment-major
  u16*  wtt   = (u16*)(ws + 33554432);         // 32 MB  bf16 W^T, fragment-major
  u16*  w234t = (u16*)(ws + 67108864);         // 16 MB  bf16 W234^T
  float* w34T = (float*)(ws + 83886080);       // 512 KB fp32 W34 transposed

  x_and_w34T  <<<8704, 256, 0, stream>>>(x, xbt, ker, w34T);
  build_w234t2<<<512, 256, 0, stream>>>(ker, w34T, w234t);
  build_wt3   <<<1024, 256, 0, stream>>>(ker, w234t, wtt);
  gemm_fm     <<<256, 256, 0, stream>>>(xbt, wtt, bias, out);
}

// Round 8
// 206.840 us; speedup vs baseline: 1.8349x; 1.8349x over previous
//
#include <hip/hip_runtime.h>
#include <hip/hip_bf16.h>

typedef unsigned short u16;
typedef __attribute__((ext_vector_type(8))) short  bf16x8;
typedef __attribute__((ext_vector_type(8))) u16    u16x8;
typedef __attribute__((ext_vector_type(4))) float  fx4;
typedef __attribute__((ext_vector_type(16))) float fx16;

// flat offsets of TT cores in the packed kernel (reference iterates k=3..0 from idx 0)
#define OFF_C0 0       // core for k=3: [8 x 256]   core0[i4][a3*8+o4]
#define OFF_C1 2048    // core for k=2: [256 x 256] core1[i3*32+a3][a2*8+o3]
#define OFF_C2 67584   // core for k=1: [256 x 256] core2[i2*32+a2][a1*8+o2]
#define OFF_C3 133120  // core for k=0: [256 x 8]   core3[i1*32+a1][o1]

// Fragment-major layouts (32x32x16 MFMA, lane mapping HW-verified in R2/R6):
//   operand: lane l holds M[r32*32 + (l&31)][k32*32 + ks*16 + (l>>5)*8 + e], e=0..7
//   flat elem index: (((k32*128 + r32)*2 + ks)*64 + l)*8 + e
// Each (k32, r32, ks) unit is 1024 contiguous bytes in exact wave-lane order:
// gld16 staging sources are contiguous, LDS stays linear, ds_read_b128 is lane-linear
// (64 lanes x 16B contiguous = 2 lanes/bank-quad = conflict-free, m136).

static __device__ __forceinline__ u16 f2bf(float f) {
  union { __hip_bfloat16 h; u16 u; } cv;
  cv.h = __float2bfloat16(f);
  return cv.u;
}
static __device__ __forceinline__ float bf2f(u16 u) {
  union { u16 u; __hip_bfloat16 h; } cv;
  cv.u = u;
  return __bfloat162float(cv.h);
}

// fused: blocks [0,8192): x fp32 -> bf16 in fragment-major xbt; blocks [8192,8704): W34T.
__global__ void x_and_w34T(const float* __restrict__ x, u16* __restrict__ xbt,
                           const float* __restrict__ ker, float* __restrict__ w34T) {
  if (blockIdx.x < 8192) {
    int t = blockIdx.x * 256 + threadIdx.x;        // 2,097,152 threads, one 16B chunk each
    int l = t & 63, ks = (t >> 6) & 1, m32 = (t >> 7) & 127, k32 = t >> 14;
    int row = m32 * 32 + (l & 31);
    int col = k32 * 32 + ks * 16 + (l >> 5) * 8;
    const fx4* p = (const fx4*)(x + (size_t)row * 4096 + col);
    fx4 v0 = p[0], v1 = p[1];
    u16 tmp[8];
#pragma unroll
    for (int q = 0; q < 4; ++q) tmp[q] = f2bf(v0[q]);
#pragma unroll
    for (int q = 0; q < 4; ++q) tmp[4 + q] = f2bf(v1[q]);
    *(u16x8*)(xbt + (size_t)t * 8) = *(const u16x8*)tmp;
  } else {
    int t = (blockIdx.x - 8192) * 256 + threadIdx.x;   // 131072 threads
    int i34 = t & 63, c = t >> 6;
    int a2 = c >> 6, o3 = (c >> 3) & 7, o4 = c & 7;
    int i3 = i34 >> 3, i4 = i34 & 7;
    float s = 0.f;
#pragma unroll 8
    for (int a3 = 0; a3 < 32; ++a3) {
      float k1 = ker[OFF_C1 + (i3 * 32 + a3) * 256 + a2 * 8 + o3];
      float k0 = ker[OFF_C0 + i4 * 256 + a3 * 8 + o4];
      s += k1 * k0;
    }
    w34T[c * 64 + i34] = s;
  }
}

// W234t[(a1*64+o2*8+o3)*8 + o4][i234] = sum_a2 core2[i2*32+a2, a1*8+o2] * W34T[a2*64+o3*8+o4][i34]
__global__ void build_w234t2(const float* __restrict__ ker, const float* __restrict__ w34T,
                             u16* __restrict__ w234t) {
  int t = blockIdx.x * 256 + threadIdx.x;   // 131072 threads
  int i234 = t & 511, g = t >> 9;           // g = a1*8 + o3
  int a1 = g >> 3, o3 = g & 7;
  int i2 = i234 >> 6, i34 = i234 & 63;
  float acc[8][8];
#pragma unroll
  for (int a = 0; a < 8; ++a)
#pragma unroll
    for (int b = 0; b < 8; ++b) acc[a][b] = 0.f;
  for (int a2 = 0; a2 < 32; ++a2) {
    float w[8];
#pragma unroll
    for (int o4 = 0; o4 < 8; ++o4)
      w[o4] = w34T[(a2 * 64 + o3 * 8 + o4) * 64 + i34];
#pragma unroll
    for (int o2 = 0; o2 < 8; ++o2) {
      float c2 = ker[OFF_C2 + (i2 * 32 + a2) * 256 + a1 * 8 + o2];
#pragma unroll
      for (int o4 = 0; o4 < 8; ++o4) acc[o2][o4] += c2 * w[o4];
    }
  }
#pragma unroll
  for (int o2 = 0; o2 < 8; ++o2) {
    int cg = a1 * 64 + o2 * 8 + o3;
#pragma unroll
    for (int o4 = 0; o4 < 8; ++o4)
      w234t[(cg * 8 + o4) * 512 + i234] = f2bf(acc[o2][o4]);
  }
}

// Wt[j,i] -> fragment-major wtt. Thread owns (j234, i234), reads each w234t element once.
__global__ void build_wt3(const float* __restrict__ ker, const u16* __restrict__ w234t,
                          u16* __restrict__ wtt) {
  int t = blockIdx.x * 256 + threadIdx.x;   // 262144 threads
  int i234 = t & 511, j234 = t >> 9;
  float acc[8][8];
#pragma unroll
  for (int a = 0; a < 8; ++a)
#pragma unroll
    for (int b = 0; b < 8; ++b) acc[a][b] = 0.f;
  for (int a1 = 0; a1 < 32; ++a1) {
    float w = bf2f(w234t[(a1 * 512 + j234) * 512 + i234]);
#pragma unroll
    for (int i1 = 0; i1 < 8; ++i1) {
      const float* c3 = ker + OFF_C3 + (i1 * 32 + a1) * 8;
#pragma unroll
      for (int o1 = 0; o1 < 8; ++o1) acc[i1][o1] += c3[o1] * w;
    }
  }
  // dest: j = o1*512 + j234 (N), i = i1*512 + i234 (K)
  const int ks = (i234 >> 4) & 1;
  const int l  = (j234 & 31) | (((i234 >> 3) & 1) << 5);
  const int e  = i234 & 7;
#pragma unroll
  for (int o1 = 0; o1 < 8; ++o1) {
    const int n32 = o1 * 16 + (j234 >> 5);
#pragma unroll
    for (int i1 = 0; i1 < 8; ++i1) {
      const int k32 = i1 * 16 + (i234 >> 5);
      wtt[(((size_t)(k32 * 128 + n32) * 2 + ks) * 64 + l) * 8 + e] = f2bf(acc[i1][o1]);
    }
  }
}

__device__ __forceinline__ void gld16(const u16* g, u16* l) {
  __builtin_amdgcn_global_load_lds((const __attribute__((address_space(1))) void*)g,
                                   (__attribute__((address_space(3))) void*)l, 16, 0, 0);
}

// C[4096,4096] = A*B^T + bias from fragment-major xbt/wtt.
// 256x256 tile, BK=32, 8 waves (2Mx4N), per-wave 128x64 = 4x2 frags of 32x32x16 MFMA.
// R3's proven free-run schedule: per K-tile 12 lane-linear ds_read_b128 + 4 gld16
// (stage t+3) + 16 MFMA + vmcnt(8) + ONE barrier. 4 LDS bufs (128 KB), 2 waves/SIMD.
__global__ __launch_bounds__(512, 2) void gemm_fm8(const u16* __restrict__ A, const u16* __restrict__ B,
                                                   const float* __restrict__ bias, float* __restrict__ C) {
  __shared__ __align__(16) u16 sh[65536];  // elems: A bufs [0,32768), B bufs [32768,65536)

  const int tid = threadIdx.x;
  const int lane = tid & 63;
  const int wave = tid >> 6;
  const int wm = wave >> 2, wn = wave & 3;
  const int l32 = lane & 31, hk = lane >> 5;

  // XCD-aware block swizzle (256 blocks, 256%8==0)
  const int bid = blockIdx.x;
  const int wg = (bid & 7) * 32 + (bid >> 3);
  const int bm = (wg >> 4) * 256, bn = (wg & 15) * 256;

  // staging: block's A-chunk per K-tile = 8192 elems contiguous starting at
  // (k32*128 + bm/32)*1024; thread reads elems tid*8 and 4096+tid*8 (2 gld16), same for B.
  const size_t abase = (size_t)(bm >> 5) * 1024 + tid * 8;
  const size_t bbase = (size_t)(bn >> 5) * 1024 + tid * 8;
  const int ldsW = wave * 512;  // elems: wave-uniform dest base offset within a buffer

  // fragment read element-offsets within a buffer (8192 elems = 16 units of 512):
  // A unit (m,ks) = (wm*4+m)*2+ks ; B unit (n,ks) = (wn*2+n)*2+ks ; + lane*8
  int aoff[4][2], boff[2][2];
#pragma unroll
  for (int m = 0; m < 4; ++m)
#pragma unroll
    for (int ks = 0; ks < 2; ++ks)
      aoff[m][ks] = (((wm * 4 + m) * 2 + ks) * 64 + lane) * 8;
#pragma unroll
  for (int n = 0; n < 2; ++n)
#pragma unroll
    for (int ks = 0; ks < 2; ++ks)
      boff[n][ks] = (((wn * 2 + n) * 2 + ks) * 64 + lane) * 8;

  fx16 acc[4][2];
#pragma unroll
  for (int m = 0; m < 4; ++m)
#pragma unroll
    for (int n = 0; n < 2; ++n)
#pragma unroll
      for (int q = 0; q < 16; ++q) acc[m][n][q] = 0.f;

#define STAGE(buf, tt) do { const size_t ko = (size_t)((tt) & 127) * 131072; \
    u16* a_ = sh + (buf) * 8192 + ldsW; u16* b_ = sh + 32768 + (buf) * 8192 + ldsW; \
    gld16(A + abase + ko, a_); \
    gld16(A + abase + ko + 4096, a_ + 4096); \
    gld16(B + bbase + ko, b_); \
    gld16(B + bbase + ko + 4096, b_ + 4096); } while (0)

  // prologue: stage tiles 0,1,2 (12 loads/thread); wait tile0 landed (retire oldest 4)
  STAGE(0, 0);
  STAGE(1, 1);
  STAGE(2, 2);
  asm volatile("s_waitcnt vmcnt(8)" ::: "memory");
  __builtin_amdgcn_s_barrier();

  for (int t = 0; t < 128; ++t) {
    const u16* Ap = sh + (t & 3) * 8192;
    const u16* Bp = sh + 32768 + (t & 3) * 8192;
    const int qb = (t + 3) & 3;

    // all 12 lane-linear fragment reads up front; compiler inserts counted lgkmcnt.
    bf16x8 av[4][2], bv[2][2];
#pragma unroll
    for (int m = 0; m < 4; ++m)
#pragma unroll
      for (int ks = 0; ks < 2; ++ks) av[m][ks] = *(const bf16x8*)(Ap + aoff[m][ks]);
#pragma unroll
    for (int n = 0; n < 2; ++n)
#pragma unroll
      for (int ks = 0; ks < 2; ++ks) bv[n][ks] = *(const bf16x8*)(Bp + boff[n][ks]);

    STAGE(qb, t + 3);   // HBM latency hides under this tile's MFMAs

    __builtin_amdgcn_s_setprio(1);
#pragma unroll
    for (int ks = 0; ks < 2; ++ks)
#pragma unroll
      for (int m = 0; m < 4; ++m)
#pragma unroll
        for (int n = 0; n < 2; ++n)
          acc[m][n] = __builtin_amdgcn_mfma_f32_32x32x16_bf16(av[m][ks], bv[n][ks], acc[m][n], 0, 0, 0);
    __builtin_amdgcn_s_setprio(0);

    // retire tile t+1's 4 loads (needed next iteration); keep t+2,t+3's 8 in flight.
    asm volatile("s_waitcnt vmcnt(8)" ::: "memory");
    __builtin_amdgcn_s_barrier();
  }

  // epilogue: C/D layout col=lane&31, row=(reg&3)+8*(reg>>2)+4*(lane>>5)  [m74/m101, R2-verified]
#pragma unroll
  for (int n = 0; n < 2; ++n) {
    const int col = bn + wn * 64 + n * 32 + l32;
    const float bvl = bias[col];
#pragma unroll
    for (int m = 0; m < 4; ++m) {
      const int r0 = bm + wm * 128 + m * 32 + 4 * hk;
#pragma unroll
      for (int q = 0; q < 16; ++q) {
        const int row = r0 + (q & 3) + 8 * (q >> 2);
        C[(size_t)row * 4096 + col] = acc[m][n][q] + bvl;
      }
    }
  }
#undef STAGE
}

extern "C" void kernel_launch(void* const* d_in, const int* in_sizes, int n_in,
                              void* d_out, int out_size, void* d_ws, size_t ws_size,
                              hipStream_t stream) {
  const float* x    = (const float*)d_in[0];
  const float* ker  = (const float*)d_in[1];
  const float* bias = (const float*)d_in[2];
  float* out = (float*)d_out;

  char* ws = (char*)d_ws;
  u16*  xbt   = (u16*)ws;                      // 32 MB  bf16 x, fragment-major
  u16*  wtt   = (u16*)(ws + 33554432);         // 32 MB  bf16 W^T, fragment-major
  u16*  w234t = (u16*)(ws + 67108864);         // 16 MB  bf16 W234^T
  float* w34T = (float*)(ws + 83886080);       // 512 KB fp32 W34 transposed

  x_and_w34T  <<<8704, 256, 0, stream>>>(x, xbt, ker, w34T);
  build_w234t2<<<512, 256, 0, stream>>>(ker, w34T, w234t);
  build_wt3   <<<1024, 256, 0, stream>>>(ker, w234t, wtt);
  gemm_fm8    <<<256, 512, 0, stream>>>(xbt, wtt, bias, out);
}